// Round 1
// baseline (848.828 us; speedup 1.0000x reference)
//
#include <hip/hip_runtime.h>
#include <stdint.h>

#define B_ 4
#define S_ 2048
#define D_ 2048
#define H_ 2560
#define O_ 2048
#define M_ (B_*S_)   // 8192 rows
#define NCH 16       // scan S-chunks
#define LCH (S_/NCH) // 128

typedef __attribute__((ext_vector_type(8))) short bf16x8;
typedef __attribute__((ext_vector_type(4))) float f32x4;

typedef const __attribute__((address_space(1))) unsigned int* gp32;
typedef __attribute__((address_space(3))) unsigned int* lp32;

__device__ __forceinline__ void async_cp16(const unsigned short* g, unsigned short* l) {
    __builtin_amdgcn_global_load_lds((gp32)g, (lp32)l, 16, 0, 0);
}

__device__ __forceinline__ unsigned short f2bf(float f) {
    unsigned int x = __float_as_uint(f);
    x += 0x7fffu + ((x >> 16) & 1u);   // round-to-nearest-even
    return (unsigned short)(x >> 16);
}
__device__ __forceinline__ float bf2f(unsigned short s) {
    return __uint_as_float(((unsigned int)s) << 16);
}
__device__ __forceinline__ float4 ld_bf4(const unsigned short* p) {
    const uint2 u = *(const uint2*)p;
    float4 r;
    r.x = bf2f((unsigned short)(u.x & 0xffffu));
    r.y = bf2f((unsigned short)(u.x >> 16));
    r.z = bf2f((unsigned short)(u.y & 0xffffu));
    r.w = bf2f((unsigned short)(u.y >> 16));
    return r;
}
__device__ __forceinline__ float fast_sigmoid(float x) { return 1.0f / (1.0f + __expf(-x)); }
__device__ __forceinline__ float gelu_tanh(float x) {
    // jax.nn.gelu approximate=True
    float t = 0.7978845608028654f * (x + 0.044715f * x * x * x);
    float e = __expf(2.0f * t);
    float th = 1.0f - 2.0f / (e + 1.0f);
    return 0.5f * x * (1.0f + th);
}

// ---------------- cast x fp32 -> bf16 ----------------
__global__ void cast_x_kernel(const float* __restrict__ in, unsigned short* __restrict__ out, int n4) {
    int gid = blockIdx.x * 256 + threadIdx.x;
    if (gid >= n4) return;
    const float4 v = ((const float4*)in)[gid];
    union { unsigned short s[4]; uint2 u; } pk;
    pk.s[0] = f2bf(v.x); pk.s[1] = f2bf(v.y); pk.s[2] = f2bf(v.z); pk.s[3] = f2bf(v.w);
    ((uint2*)out)[gid] = pk.u;
}

// ---------------- transpose+cast: in [K,N] fp32 -> out [N,K] bf16 ----------------
__global__ void transpose_cast_kernel(const float* __restrict__ in, unsigned short* __restrict__ out,
                                      int K, int N) {
    __shared__ float tile[64][65];
    const int t = threadIdx.x;
    const int k0 = blockIdx.y * 64, n0 = blockIdx.x * 64;
    const int r = t >> 4, c4 = (t & 15) * 4;
    #pragma unroll
    for (int p = 0; p < 4; ++p) {
        const float4 v = *(const float4*)(in + (size_t)(k0 + p*16 + r) * N + n0 + c4);
        tile[p*16 + r][c4+0] = v.x;
        tile[p*16 + r][c4+1] = v.y;
        tile[p*16 + r][c4+2] = v.z;
        tile[p*16 + r][c4+3] = v.w;
    }
    __syncthreads();
    #pragma unroll
    for (int p = 0; p < 4; ++p) {
        const int nn = n0 + p*16 + r;
        union { unsigned short s[4]; uint2 u; } pk;
        #pragma unroll
        for (int j = 0; j < 4; ++j) pk.s[j] = f2bf(tile[c4 + j][p*16 + r]);
        *(uint2*)(out + (size_t)nn * K + k0 + c4) = pk.u;
    }
}

// ---------------- bf16 MFMA GEMM, 256x256 tile, BK=64, 8-phase schedule ----------------
// 512 threads = 8 waves (2M x 4N); per-wave output 128x64 = acc[8][4] f32x4.
// LDS 128 KiB: double-buffered A[256x64] + B[256x64] bf16, chunk-XOR swizzle
// applied on the GLOBAL source address (linear global_load_lds dest) and
// inverted on ds_read (both-sides involution).
// Per K-tile: 4 phases, each {ds_read subtile; stage 1 half-tile (2 loads);
// barrier; lgkmcnt(0); setprio(1); 16 MFMA; setprio(0); barrier}.
// Staging: B(t+1) during phases 1-2 (buffer dead since t-1 ph2),
//          A(t+2) during phases 3-4 (own A dead after ph2 lgkmcnt+barrier).
// Counted s_waitcnt vmcnt(4) once per K-tile at phase 4 (never 0 in loop):
// retires everything except the 2 A(t+2) half-tiles -> tile t+1 fully staged.
// MODE 0: N=5120: n<H -> left=bf16(gelu(v+b0)); n>=H -> rin=bf16(v+b1)
// MODE 1: N=5120: n<H -> r=bf16(sigmoid(v+b0)); n>=H -> i=bf16(sigmoid(v+b1))
// MODE 2: N=2048: out=fp32(v+b0)
#define GEMM_TILE(ASC, BSC, BSN, TT)                                           \
  do {                                                                         \
    const int kb_b = ((TT) + 1 < nt) ? ((TT) + 1) * 64 : 0;                    \
    const int kb_a = ((TT) + 2 < nt) ? ((TT) + 2) * 64 : 0;                    \
    /* ---- phase 1: read a0,b0; stage B(t+1).lo; MFMA m0n0 ---- */            \
    _Pragma("unroll")                                                          \
    for (int f = 0; f < 4; ++f) {                                              \
      a0[f][0] = *(const bf16x8*)(ASC + rbaseA + f * 1024 + ch0);              \
      a0[f][1] = *(const bf16x8*)(ASC + rbaseA + f * 1024 + ch1);              \
    }                                                                          \
    _Pragma("unroll")                                                          \
    for (int f = 0; f < 2; ++f) {                                              \
      b0[f][0] = *(const bf16x8*)(BSC + rbaseB + f * 1024 + ch0);              \
      b0[f][1] = *(const bf16x8*)(BSC + rbaseB + f * 1024 + ch1);              \
    }                                                                          \
    async_cp16(gB + kb_b,          BSN + ldst);                                \
    async_cp16(gB + kb_b + gr64,   BSN + ldst + 4096);                         \
    __builtin_amdgcn_s_barrier();                                              \
    asm volatile("s_waitcnt lgkmcnt(0)" ::: "memory");                         \
    __builtin_amdgcn_sched_barrier(0);                                         \
    __builtin_amdgcn_s_setprio(1);                                             \
    _Pragma("unroll")                                                          \
    for (int ks = 0; ks < 2; ++ks)                                             \
      _Pragma("unroll")                                                        \
      for (int f = 0; f < 4; ++f)                                              \
        _Pragma("unroll")                                                      \
        for (int g = 0; g < 2; ++g)                                            \
          acc[f][g] = __builtin_amdgcn_mfma_f32_16x16x32_bf16(                 \
              a0[f][ks], b0[g][ks], acc[f][g], 0, 0, 0);                       \
    __builtin_amdgcn_s_setprio(0);                                             \
    __builtin_amdgcn_s_barrier();                                              \
    __builtin_amdgcn_sched_barrier(0);                                         \
    /* ---- phase 2: read a1; stage B(t+1).hi; MFMA m1n0 ---- */               \
    _Pragma("unroll")                                                          \
    for (int f = 0; f < 4; ++f) {                                              \
      a1[f][0] = *(const bf16x8*)(ASC + rbaseA + 4096 + f * 1024 + ch0);       \
      a1[f][1] = *(const bf16x8*)(ASC + rbaseA + 4096 + f * 1024 + ch1);       \
    }                                                                          \
    async_cp16(gB + kb_b + 2 * gr64, BSN + 8192 + ldst);                       \
    async_cp16(gB + kb_b + 3 * gr64, BSN + 8192 + ldst + 4096);                \
    __builtin_amdgcn_s_barrier();                                              \
    asm volatile("s_waitcnt lgkmcnt(0)" ::: "memory");                         \
    __builtin_amdgcn_sched_barrier(0);                                         \
    __builtin_amdgcn_s_setprio(1);                                             \
    _Pragma("unroll")                                                          \
    for (int ks = 0; ks < 2; ++ks)                                             \
      _Pragma("unroll")                                                        \
      for (int f = 0; f < 4; ++f)                                              \
        _Pragma("unroll")                                                      \
        for (int g = 0; g < 2; ++g)                                            \
          acc[4 + f][g] = __builtin_amdgcn_mfma_f32_16x16x32_bf16(             \
              a1[f][ks], b0[g][ks], acc[4 + f][g], 0, 0, 0);                   \
    __builtin_amdgcn_s_setprio(0);                                             \
    __builtin_amdgcn_s_barrier();                                              \
    __builtin_amdgcn_sched_barrier(0);                                         \
    /* ---- phase 3: read b1; stage A(t+2).lo; MFMA m0n1 ---- */               \
    _Pragma("unroll")                                                          \
    for (int f = 0; f < 2; ++f) {                                              \
      b1[f][0] = *(const bf16x8*)(BSC + rbaseB + 2048 + f * 1024 + ch0);       \
      b1[f][1] = *(const bf16x8*)(BSC + rbaseB + 2048 + f * 1024 + ch1);       \
    }                                                                          \
    async_cp16(gA + kb_a,        ASC + ldst);                                  \
    async_cp16(gA + kb_a + gr64, ASC + ldst + 4096);                           \
    __builtin_amdgcn_s_barrier();                                              \
    asm volatile("s_waitcnt lgkmcnt(0)" ::: "memory");                         \
    __builtin_amdgcn_sched_barrier(0);                                         \
    __builtin_amdgcn_s_setprio(1);                                             \
    _Pragma("unroll")                                                          \
    for (int ks = 0; ks < 2; ++ks)                                             \
      _Pragma("unroll")                                                        \
      for (int f = 0; f < 4; ++f)                                              \
        _Pragma("unroll")                                                      \
        for (int g = 0; g < 2; ++g)                                            \
          acc[f][2 + g] = __builtin_amdgcn_mfma_f32_16x16x32_bf16(             \
              a0[f][ks], b1[g][ks], acc[f][2 + g], 0, 0, 0);                   \
    __builtin_amdgcn_s_setprio(0);                                             \
    __builtin_amdgcn_s_barrier();                                              \
    __builtin_amdgcn_sched_barrier(0);                                         \
    /* ---- phase 4: stage A(t+2).hi; vmcnt(4); MFMA m1n1 ---- */              \
    async_cp16(gA + kb_a + 2 * gr64, ASC + 8192 + ldst);                       \
    async_cp16(gA + kb_a + 3 * gr64, ASC + 8192 + ldst + 4096);                \
    asm volatile("s_waitcnt vmcnt(4)" ::: "memory");                           \
    __builtin_amdgcn_sched_barrier(0);                                         \
    __builtin_amdgcn_s_barrier();                                              \
    __builtin_amdgcn_s_setprio(1);                                             \
    _Pragma("unroll")                                                          \
    for (int ks = 0; ks < 2; ++ks)                                             \
      _Pragma("unroll")                                                        \
      for (int f = 0; f < 4; ++f)                                              \
        _Pragma("unroll")                                                      \
        for (int g = 0; g < 2; ++g)                                            \
          acc[4 + f][2 + g] = __builtin_amdgcn_mfma_f32_16x16x32_bf16(         \
              a1[f][ks], b1[g][ks], acc[4 + f][2 + g], 0, 0, 0);               \
    __builtin_amdgcn_s_setprio(0);                                             \
    __builtin_amdgcn_s_barrier();                                              \
    __builtin_amdgcn_sched_barrier(0);                                         \
  } while (0)

template <int MODE>
__global__ __launch_bounds__(512, 2) void gemm_kernel(
        const unsigned short* __restrict__ A,
        const unsigned short* __restrict__ Bt,
        const int K,
        const float* __restrict__ bias0,
        const float* __restrict__ bias1,
        void* __restrict__ out0,
        void* __restrict__ out1)
{
    __shared__ __align__(16) unsigned short As0[256*64];
    __shared__ __align__(16) unsigned short As1[256*64];
    __shared__ __align__(16) unsigned short Bs0[256*64];
    __shared__ __align__(16) unsigned short Bs1[256*64];

    const int t = threadIdx.x;

    // bijective XCD swizzle (all grids here are %8 == 0)
    const int nx = gridDim.x;
    const int nwg = gridDim.x * gridDim.y;
    int lin = blockIdx.y * nx + blockIdx.x;
    lin = (lin & 7) * (nwg >> 3) + (lin >> 3);
    const int m0 = (lin / nx) * 256;
    const int n0 = (lin % nx) * 256;

    // staging: thread t covers row t>>3 (+64 per second cp), chunk (t&7)^(row&7)
    const int srow = t >> 3;                        // 0..63
    const int scol = ((t & 7) ^ (srow & 7)) * 8;
    const unsigned short* gA = A  + (size_t)(m0 + srow) * K + scol;
    const unsigned short* gB = Bt + (size_t)(n0 + srow) * K + scol;
    const size_t gr64 = (size_t)64 * K;             // 64-row step (elements)
    const int ldst = t * 8;                         // linear LDS dest (halfwords)

    const int lane = t & 63;
    const int w = t >> 6;          // 0..7
    const int wm = w >> 2;         // 0..1  -> rows wm*128..+128
    const int wn = w & 3;          // 0..3  -> cols wn*64..+64
    const int q = lane >> 4;       // k-quad 0..3
    const int l16 = lane & 15;

    const int rbaseA = (wm * 128 + l16) * 64;       // halfword offsets
    const int rbaseB = (wn * 64 + l16) * 64;
    const int ch0 = ((q)     ^ (l16 & 7)) * 8;      // swizzled k-chunks ks=0/1
    const int ch1 = ((q + 4) ^ (l16 & 7)) * 8;

    const int nt = K >> 6;   // 32 or 40 (always even)

    f32x4 acc[8][4];
    #pragma unroll
    for (int i = 0; i < 8; ++i)
        #pragma unroll
        for (int j = 0; j < 4; ++j)
            acc[i][j] = (f32x4){0.f, 0.f, 0.f, 0.f};

    bf16x8 a0[4][2], a1[4][2], b0[2][2], b1[2][2];

    // prologue: stage tile0 A+B (8 loads), tile1 A (4 loads); wait tile0 done
    async_cp16(gA,            As0 + ldst);
    async_cp16(gA + gr64,     As0 + ldst + 4096);
    async_cp16(gA + 2*gr64,   As0 + 8192 + ldst);
    async_cp16(gA + 3*gr64,   As0 + 8192 + ldst + 4096);
    async_cp16(gB,            Bs0 + ldst);
    async_cp16(gB + gr64,     Bs0 + ldst + 4096);
    async_cp16(gB + 2*gr64,   Bs0 + 8192 + ldst);
    async_cp16(gB + 3*gr64,   Bs0 + 8192 + ldst + 4096);
    async_cp16(gA + 64,           As1 + ldst);
    async_cp16(gA + 64 + gr64,    As1 + ldst + 4096);
    async_cp16(gA + 64 + 2*gr64,  As1 + 8192 + ldst);
    async_cp16(gA + 64 + 3*gr64,  As1 + 8192 + ldst + 4096);
    asm volatile("s_waitcnt vmcnt(4)" ::: "memory");
    __builtin_amdgcn_sched_barrier(0);
    __builtin_amdgcn_s_barrier();

    for (int tt = 0; tt < nt; tt += 2) {
        GEMM_TILE(As0, Bs0, Bs1, tt);
        GEMM_TILE(As1, Bs1, Bs0, tt + 1);
    }
    asm volatile("s_waitcnt vmcnt(0)" ::: "memory");   // drain trailing prefetches

    // epilogue: C/D layout col=lane&15, row=(lane>>4)*4+reg
    const int rb = q * 4;
    if (MODE == 2) {
        float* op = (float*)out0;
        #pragma unroll
        for (int i = 0; i < 8; ++i) {
            const int rr = m0 + wm * 128 + (i >> 2) * 64 + (i & 3) * 16 + rb;
            #pragma unroll
            for (int j = 0; j < 4; ++j) {
                const int cc = n0 + wn * 64 + (j >> 1) * 32 + (j & 1) * 16 + l16;
                const float bb = bias0[cc];
                #pragma unroll
                for (int jj = 0; jj < 4; ++jj)
                    op[(size_t)(rr + jj) * O_ + cc] = acc[i][j][jj] + bb;
            }
        }
    } else {
        // N=5120 split at H_=2560 is block-uniform (n0 multiple of 256)
        const bool left = (n0 < H_);
        const float* bias = left ? bias0 : bias1;
        unsigned short* op = (unsigned short*)(left ? out0 : out1);
        const int nb = left ? n0 : (n0 - H_);
        #pragma unroll
        for (int i = 0; i < 8; ++i) {
            const int rr = m0 + wm * 128 + (i >> 2) * 64 + (i & 3) * 16 + rb;
            #pragma unroll
            for (int j = 0; j < 4; ++j) {
                const int cc = nb + wn * 64 + (j >> 1) * 32 + (j & 1) * 16 + l16;
                const float bb = bias[cc];
                #pragma unroll
                for (int jj = 0; jj < 4; ++jj) {
                    float v = acc[i][j][jj] + bb;
                    if (MODE == 0) v = left ? gelu_tanh(v) : v;
                    else           v = fast_sigmoid(v);
                    op[(size_t)(rr + jj) * H_ + cc] = f2bf(v);
                }
            }
        }
    }
}

// ---------------- causal depthwise conv (width 4), bf16 in -> bf16 out ----------------
__global__ void conv_kernel(const unsigned short* __restrict__ rin,
                            const float* __restrict__ cw,
                            const float* __restrict__ cb,
                            unsigned short* __restrict__ ub)
{
    const int gid = blockIdx.x * 256 + threadIdx.x;   // (b, s/4, h/4)
    const int h = (gid % (H_/4)) * 4;
    const int tmp = gid / (H_/4);
    const int s0 = (tmp % (S_/4)) * 4;
    const int b = tmp / (S_/4);
    const unsigned short* base = rin + (size_t)b * S_ * H_ + h;
    float4 rows[7];
    #pragma unroll
    for (int idx = 0; idx < 7; ++idx) {
        const int s = s0 - 3 + idx;
        if (s >= 0) rows[idx] = ld_bf4(base + (size_t)s * H_);
        else        rows[idx] = make_float4(0.f, 0.f, 0.f, 0.f);
    }
    float4 w[4];
    #pragma unroll
    for (int j = 0; j < 4; ++j) w[j] = *(const float4*)(cw + j * H_ + h);
    const float4 bias = *(const float4*)(cb + h);
    #pragma unroll
    for (int p = 0; p < 4; ++p) {
        float ox = bias.x, oy = bias.y, oz = bias.z, ow = bias.w;
        #pragma unroll
        for (int j = 0; j < 4; ++j) {
            ox += w[j].x * rows[p + j].x;
            oy += w[j].y * rows[p + j].y;
            oz += w[j].z * rows[p + j].z;
            ow += w[j].w * rows[p + j].w;
        }
        const size_t oidx = (size_t)b * S_ * H_ + (size_t)(s0 + p) * H_ + h;
        union { unsigned short s4[4]; uint2 uu; } pk;
        pk.s4[0] = f2bf(ox); pk.s4[1] = f2bf(oy); pk.s4[2] = f2bf(oz); pk.s4[3] = f2bf(ow);
        *(uint2*)(ub + oidx) = pk.uu;
    }
}

// ---------------- chunked RG-LRU scan (3 passes) ----------------
__global__ void scan_pass1(const unsigned short* __restrict__ rg,
                           const unsigned short* __restrict__ ig,
                           const unsigned short* __restrict__ ub,
                           const float* __restrict__ lam,
                           float* __restrict__ Asum,
                           float* __restrict__ Hend)
{
    const int tid = blockIdx.x * 256 + threadIdx.x;  // (b*NCH + c)*H + h
    const int h = tid % H_;
    const int t2 = tid / H_;
    const int c = t2 % NCH;
    const int b = t2 / NCH;
    const float kh = -8.0f * log1pf(__expf(-lam[h]));
    size_t idx = ((size_t)b * S_ + (size_t)c * LCH) * H_ + h;
    float A = 1.f, hs = 0.f;
    #pragma unroll 4
    for (int s = 0; s < LCH; ++s, idx += H_) {
        const float rv = bf2f(rg[idx]);
        const float iv = bf2f(ig[idx]);
        const float uv = bf2f(ub[idx]);
        const float a = __expf(kh * rv);
        const float beta = sqrtf(fmaxf(1.f - a * a, 1e-12f));
        hs = a * hs + beta * iv * uv;
        A *= a;
    }
    Asum[tid] = A;
    Hend[tid] = hs;
}

__global__ void scan_pass2(const float* __restrict__ Asum, float* __restrict__ Hend) {
    const int tid = blockIdx.x * 256 + threadIdx.x;   // b*H + h
    const int h = tid % H_;
    const int b = tid / H_;
    float hin = 0.f;
    #pragma unroll
    for (int c = 0; c < NCH; ++c) {
        const int q = (b * NCH + c) * H_ + h;
        const float Ac = Asum[q];
        const float he = Hend[q];
        Hend[q] = hin;
        hin = he + Ac * hin;
    }
}

__global__ void scan_pass3(const unsigned short* __restrict__ rg,
                           const unsigned short* __restrict__ ig,
                           const unsigned short* __restrict__ ub,
                           const unsigned short* __restrict__ leftb,
                           const float* __restrict__ lam,
                           const float* __restrict__ Hin,
                           unsigned short* __restrict__ lrb)
{
    const int tid = blockIdx.x * 256 + threadIdx.x;
    const int h = tid % H_;
    const int t2 = tid / H_;
    const int c = t2 % NCH;
    const int b = t2 / NCH;
    const float kh = -8.0f * log1pf(__expf(-lam[h]));
    size_t idx = ((size_t)b * S_ + (size_t)c * LCH) * H_ + h;
    float hs = Hin[tid];
    #pragma unroll 4
    for (int s = 0; s < LCH; ++s, idx += H_) {
        const float rv = bf2f(rg[idx]);
        const float iv = bf2f(ig[idx]);
        const float uv = bf2f(ub[idx]);
        const float lf = bf2f(leftb[idx]);
        const float a = __expf(kh * rv);
        const float beta = sqrtf(fmaxf(1.f - a * a, 1e-12f));
        hs = a * hs + beta * iv * uv;
        lrb[idx] = f2bf(lf * hs);
    }
}

extern "C" void kernel_launch(void* const* d_in, const int* in_sizes, int n_in,
                              void* d_out, int out_size, void* d_ws, size_t ws_size,
                              hipStream_t stream)
{
    const float* x   = (const float*)d_in[0];
    const float* Wl  = (const float*)d_in[1];
    const float* bl  = (const float*)d_in[2];
    const float* Wr  = (const float*)d_in[3];
    const float* br  = (const float*)d_in[4];
    const float* cw  = (const float*)d_in[5];
    const float* cb  = (const float*)d_in[6];
    const float* Wa  = (const float*)d_in[7];
    const float* ba  = (const float*)d_in[8];
    const float* Wi  = (const float*)d_in[9];
    const float* bi  = (const float*)d_in[10];
    const float* lam = (const float*)d_in[11];
    const float* Wo  = (const float*)d_in[12];
    const float* bo  = (const float*)d_in[13];
    float* out = (float*)d_out;
    (void)in_sizes; (void)n_in; (void)out_size;

    const size_t wWlr = (size_t)2 * H_ * D_ * 2;   // 20.97 MB
    const size_t wWai = (size_t)2 * H_ * H_ * 2;   // 26.21 MB
    const size_t wWo  = (size_t)O_ * H_ * 2;       // 10.49 MB
    auto al = [](size_t b) { return (b + 255) & ~(size_t)255; };

    // choose batch-chunking so workspace fits: nchunk in {1,2,4}
    int nchunk = 4;
    for (int n = 1; n <= 4; n *= 2) {
        const size_t Mc = M_ / n;
        const size_t Bc = Mc / S_;
        const size_t need = al(wWlr) + al(wWai) + al(wWo)
                          + 4 * al(Mc * H_ * 2)
                          + 2 * al(Bc * NCH * H_ * 4);
        if (need <= ws_size) { nchunk = n; break; }
    }
    const int Mc = M_ / nchunk;
    const int Bc = Mc / S_;
    const size_t actB = (size_t)Mc * H_ * 2;

    char* p = (char*)d_ws;
    size_t off = 0;
    auto alloc = [&](size_t bytes) -> void* {
        void* q = p + off;
        off += al(bytes);
        return q;
    };
    unsigned short* WlrT  = (unsigned short*)alloc(wWlr);
    unsigned short* WaiT  = (unsigned short*)alloc(wWai);
    unsigned short* WoT   = (unsigned short*)alloc(wWo);
    unsigned short* slotX = (unsigned short*)alloc(actB);  // xb -> rgate -> lr
    unsigned short* slotL = (unsigned short*)alloc(actB);  // left
    unsigned short* slotR = (unsigned short*)alloc(actB);  // rin -> igate
    unsigned short* slotU = (unsigned short*)alloc(actB);  // u
    float* Asum = (float*)alloc((size_t)Bc * NCH * H_ * 4);
    float* Hend = (float*)alloc((size_t)Bc * NCH * H_ * 4);

    // weight transposes (once)
    transpose_cast_kernel<<<dim3(H_/64, D_/64), dim3(256), 0, stream>>>(Wl, WlrT, D_, H_);
    transpose_cast_kernel<<<dim3(H_/64, D_/64), dim3(256), 0, stream>>>(Wr, WlrT + (size_t)H_*D_, D_, H_);
    transpose_cast_kernel<<<dim3(H_/64, H_/64), dim3(256), 0, stream>>>(Wa, WaiT, H_, H_);
    transpose_cast_kernel<<<dim3(H_/64, H_/64), dim3(256), 0, stream>>>(Wi, WaiT + (size_t)H_*H_, H_, H_);
    transpose_cast_kernel<<<dim3(O_/64, H_/64), dim3(256), 0, stream>>>(Wo, WoT, H_, O_);

    for (int c = 0; c < nchunk; ++c) {
        const float* xc = x + (size_t)c * Mc * D_;
        float* outc = out + (size_t)c * Mc * O_;
        unsigned short* xb    = slotX;
        unsigned short* leftb = slotL;
        unsigned short* rinb  = slotR;
        unsigned short* ub    = slotU;
        unsigned short* rgb   = slotX;   // xb dead after GEMM1
        unsigned short* igb   = slotR;   // rinb dead after conv
        unsigned short* lrb   = slotX;   // in-place over rgate in pass 3

        cast_x_kernel<<<dim3(Mc*D_/4/256), dim3(256), 0, stream>>>(xc, xb, Mc*D_/4);
        gemm_kernel<0><<<dim3((2*H_)/256, Mc/256), dim3(512), 0, stream>>>(xb, WlrT, D_, bl, br, leftb, rinb);
        conv_kernel<<<dim3(Bc*S_*H_/16/256), dim3(256), 0, stream>>>(rinb, cw, cb, ub);
        gemm_kernel<1><<<dim3((2*H_)/256, Mc/256), dim3(512), 0, stream>>>(ub, WaiT, H_, ba, bi, rgb, igb);
        scan_pass1<<<dim3(Bc*NCH*H_/256), dim3(256), 0, stream>>>(rgb, igb, ub, lam, Asum, Hend);
        scan_pass2<<<dim3(Bc*H_/256), dim3(256), 0, stream>>>(Asum, Hend);
        scan_pass3<<<dim3(Bc*NCH*H_/256), dim3(256), 0, stream>>>(rgb, igb, ub, leftb, lam, Hend, lrb);
        gemm_kernel<2><<<dim3(O_/256, Mc/256), dim3(512), 0, stream>>>(lrb, WoT, H_, bo, nullptr, outc, nullptr);
    }
}